// Round 1
// baseline (453.151 us; speedup 1.0000x reference)
//
#include <hip/hip_runtime.h>
#include <hip/hip_bf16.h>
#include <math.h>

#define B_   512
#define I_   8
#define C_   1152
#define J_   10
#define S_   16
#define K1   9216
#define NKB  288     // sgemm K-blocks (K=9216/32)
#define KBT  16      // tgemm K-blocks (K=512/32)
#define NBLK 320     // persistent grid: 32 nt-tiles x 10 j

typedef short short8 __attribute__((ext_vector_type(8)));
typedef float floatx4 __attribute__((ext_vector_type(4)));

__device__ inline unsigned short f2bf(float f) {
    unsigned int u = __float_as_uint(f);
    return (unsigned short)((u + 0x7FFFu + ((u >> 16) & 1u)) >> 16);
}
__device__ inline unsigned int pack2(float a, float b) {
    __hip_bfloat162 h = __float22bfloat162_rn(float2{a, b});
    return *reinterpret_cast<unsigned int*>(&h);
}

// ---------------------------------------------------------------------------
// Grid-wide barrier: monotone arrival counter, epoch targets (no reset -> no
// ABA). Safe: grid(320) with __launch_bounds__(512,4) => VGPR<=128, LDS 40KB
// => >=2 blocks/CU => all 320 blocks co-resident (<= 512 capacity).
// Agent-scope release/acquire handles cross-XCD L2 writeback/invalidate.
__device__ inline void gsync(int* bar, int target) {
    __syncthreads();
    if (threadIdx.x == 0) {
        __threadfence();
        __hip_atomic_fetch_add(bar, 1, __ATOMIC_RELEASE, __HIP_MEMORY_SCOPE_AGENT);
        while (__hip_atomic_load(bar, __ATOMIC_ACQUIRE, __HIP_MEMORY_SCOPE_AGENT) < target)
            __builtin_amdgcn_s_sleep(2);
    }
    __syncthreads();
}

// ---------------------------------------------------------------------------
// SGEMM phase (verbatim body from verified k_sgemm_f).
// MODE 0: uniform cnorm=0.1; MODE 1: softmax fold -> Vf; MODE 2: fold -> out.
template<int MODE>
__device__ __forceinline__ void sgemm_phase(
        float* smf,
        const short8* __restrict__ Wf, const short8* __restrict__ Bs,
        const float* __restrict__ b_ij,
        unsigned short* __restrict__ Vf, float* __restrict__ out) {
    const int t = threadIdx.x, w = t >> 6, L = t & 63, quad = L >> 4;
    const int j  = blockIdx.x >> 5;      // 0..9
    const int nt = blockIdx.x & 31;      // 16-b tile, 0..31

    if (MODE) {
        for (int c = t; c < C_; c += 512) {
            float bv[J_], mx = -1e30f;
            #pragma unroll
            for (int jj = 0; jj < J_; jj++) {
                bv[jj] = b_ij[c * J_ + jj]; mx = fmaxf(mx, bv[jj]);
            }
            float sum = 0.0f;
            #pragma unroll
            for (int jj = 0; jj < J_; jj++) sum += __expf(bv[jj] - mx);
            smf[c] = __expf(bv[j] - mx) / sum;
        }
    }
    __syncthreads();

    const short8* pA = Wf + ((size_t)j * NKB + w * 36) * 64 + L;
    const short8* pB = Bs + ((size_t)nt * NKB + w * 36) * 64 + L;
    floatx4 acc = {0.f, 0.f, 0.f, 0.f};
    if (MODE) {
        #pragma unroll 6
        for (int i = 0; i < 36; i++) {
            short8 a = pA[i * 64];
            const int cb = i * 32 + quad * 8;     // (w*36*32) % 1152 == 0
            float4 cl = *(const float4*)&smf[cb];
            float4 ch = *(const float4*)&smf[cb + 4];
            float cn8[8] = {cl.x, cl.y, cl.z, cl.w, ch.x, ch.y, ch.z, ch.w};
            unsigned int* au = (unsigned int*)&a;
            short8 a2; unsigned int* ao = (unsigned int*)&a2;
            #pragma unroll
            for (int h = 0; h < 4; h++) {
                float f0 = __uint_as_float(au[h] << 16)         * cn8[2 * h];
                float f1 = __uint_as_float(au[h] & 0xffff0000u) * cn8[2 * h + 1];
                ao[h] = pack2(f0, f1);
            }
            acc = __builtin_amdgcn_mfma_f32_16x16x32_bf16(a2, pB[i * 64], acc, 0, 0, 0);
        }
    } else {
        #pragma unroll 6
        for (int i = 0; i < 36; i++)
            acc = __builtin_amdgcn_mfma_f32_16x16x32_bf16(pA[i * 64], pB[i * 64], acc, 0, 0, 0);
    }

    const int col = L & 15, rw = quad << 2;
    float* base = &smf[1152 + w * 256];
    #pragma unroll
    for (int r = 0; r < 4; r++)
        base[(rw + r) * 16 + col] = acc[r];
    __syncthreads();

    if (t < 16) {                        // reduce 8 partials + squash (bl = t)
        float sv[S_]; float msq = 0.f;
        #pragma unroll
        for (int s = 0; s < S_; s++) {
            float a = 0.f;
            #pragma unroll
            for (int w8 = 0; w8 < 8; w8++)
                a += smf[1152 + w8 * 256 + s * 16 + t];
            if (MODE == 0) a *= 0.1f;
            sv[s] = a; msq += a * a;
        }
        const float scale = msq / ((1.f + msq) * sqrtf(msq));
        const int b = nt * 16 + t;       // global b (0..511)
        if (MODE < 2) {
            const int kb = b >> 5, lh = (b >> 3) & 3, e = b & 7;
            #pragma unroll
            for (int s = 0; s < S_; s++)
                Vf[((size_t)(j * KBT + kb) * 64 + (s | (lh << 4))) * 8 + e] =
                    f2bf(sv[s] * scale);
        } else {
            float o16[S_];
            #pragma unroll
            for (int s = 0; s < S_; s++) o16[s] = sv[s] * scale;
            float* dst = &out[((size_t)b * J_ + j) * S_];
            #pragma unroll
            for (int r4 = 0; r4 < 4; r4++)
                *(float4*)(dst + r4 * 4) = *(float4*)(o16 + r4 * 4);
        }
    }
    // no trailing __syncthreads: the following gsync() provides it
}

// ---------------------------------------------------------------------------
// TGEMM phase (verbatim body): 5760 wave-tasks redistributed over 2560 waves.
__device__ __forceinline__ void tgemm_phase(
        const short8* __restrict__ Vf, const short8* __restrict__ Bt,
        const unsigned short* __restrict__ W2, float* __restrict__ b_ij) {
    const int t = threadIdx.x, w = t >> 6, L = t & 63;
    for (int tau = blockIdx.x * 8 + w; tau < 5760; tau += NBLK * 8) {
        const int j = tau / 576, nt = tau % 576;
        const short8* pA = Vf + (size_t)j * KBT * 64 + L;
        const short8* pB = Bt + (size_t)nt * KBT * 64 + L;
        floatx4 a = {0.f, 0.f, 0.f, 0.f};
        #pragma unroll
        for (int kb = 0; kb < KBT; kb++)
            a = __builtin_amdgcn_mfma_f32_16x16x32_bf16(pA[kb * 64], pB[kb * 64], a, 0, 0, 0);
        const int col = L & 15, rw = (L >> 4) << 2;
        const int i = nt / 72;
        const int c = (nt % 72) * 16 + col;
        const unsigned short* wp = W2 + ((size_t)(j * 8 + i) * C_ + c) * 16 + rw;
        uint2 wv = *(const uint2*)wp;
        float p = a[0] * __uint_as_float((unsigned int)wv.x << 16)
                + a[1] * __uint_as_float(wv.x & 0xffff0000u)
                + a[2] * __uint_as_float((unsigned int)wv.y << 16)
                + a[3] * __uint_as_float(wv.y & 0xffff0000u);
        p += __shfl_xor(p, 16);
        p += __shfl_xor(p, 32);
        if ((L >> 4) == 0)
            atomicAdd(&b_ij[c * J_ + j], p * (1.0f / 512.f));
    }
}

// ---------------------------------------------------------------------------
// Fused persistent kernel: pack | s0 | t0 | s1 | t1 | s2 with 5 grid syncs.
__global__ __launch_bounds__(512, 4) void k_fused(
        const float* __restrict__ x, const float* __restrict__ W,
        float* __restrict__ ws, float* __restrict__ out, int* __restrict__ bar) {
    __shared__ float lds[10240];
    const int t = threadIdx.x, w = t >> 6, L = t & 63, quad = L >> 4;

    float* Bs_f = ws;                    // bf16 Bs   (9.4 MB region)
    float* Bt_f = Bs_f + 2359296;        // bf16 Bt
    float* Wf_f = Bt_f + 2359296;        // bf16 Wf
    float* W2_f = Wf_f + 737280;         // bf16 W2
    float* Vf_f = W2_f + 737280;         // bf16 Vf
    float* bij  = Vf_f + 40960;          // f32 b_ij

    uint4* Bs4 = (uint4*)Bs_f;
    uint4* Bt4 = (uint4*)Bt_f;
    uint4* Wf4 = (uint4*)Wf_f;
    unsigned short* W2s = (unsigned short*)W2_f;

    // ---------------- phase P: pack (721 tasks over 320 blocks) ------------
    for (int task = blockIdx.x; task < 721; task += NBLK) {
        if (task < 576) {                       // ---- x tile -> Bs + Bt
            const int bt = task / 36, kt = task % 36;
            const int b0 = bt * 32, k0 = kt * 256;
            #pragma unroll
            for (int p = 0; p < 4; p++) {
                int f4 = p * 512 + t;
                int row = f4 >> 6, c4 = (f4 & 63) << 2;
                *(float4*)&lds[row * 260 + c4] =
                    *(const float4*)&x[(size_t)(b0 + row) * K1 + k0 + c4];
            }
            __syncthreads();
            #pragma unroll
            for (int p = 0; p < 2; p++) {
                const int bl = p * 16 + (L & 15);
                const float* s = &lds[bl * 260 + w * 32 + quad * 8];
                uint4 o;
                o.x = pack2(s[0], s[1]); o.y = pack2(s[2], s[3]);
                o.z = pack2(s[4], s[5]); o.w = pack2(s[6], s[7]);
                Bs4[((size_t)(bt * 2 + p) * NKB + kt * 8 + w) * 64 + L] = o;
            }
            #pragma unroll
            for (int p = 0; p < 2; p++) {
                const int ntl = w * 2 + p;
                const int nl = ntl * 16 + (L & 15);
                float v[8];
                #pragma unroll
                for (int e = 0; e < 8; e++) v[e] = lds[(quad * 8 + e) * 260 + nl];
                uint4 o;
                o.x = pack2(v[0], v[1]); o.y = pack2(v[2], v[3]);
                o.z = pack2(v[4], v[5]); o.w = pack2(v[6], v[7]);
                Bt4[((size_t)(kt * 16 + ntl) * KBT + bt) * 64 + L] = o;
            }
        } else if (task < 720) {                // ---- W chunk -> Wf + W2
            const int c0 = (task - 576) * 8;
            #pragma unroll
            for (int p = 0; p < 5; p++) {
                int f4 = p * 512 + t;
                int cc = f4 / 320, off4 = (f4 % 320) << 2;
                *(float4*)&lds[cc * 1280 + off4] =
                    *(const float4*)&W[(size_t)(c0 + cc) * 1280 + off4];
            }
            __syncthreads();
            #pragma unroll
            for (int p = 0; p < 3; p++) {
                int o = p * 512 + t;
                if (o < 1280) {
                    int j = o >> 7, i = (o >> 4) & 7, m = o & 15;
                    int k0w = i * C_ + c0;
                    int Lw = m | (((k0w >> 3) & 3) << 4);
                    float v[8];
                    #pragma unroll
                    for (int e = 0; e < 8; e++)
                        v[e] = lds[e * 1280 + j * 128 + m * 8 + i];
                    uint4 og;
                    og.x = pack2(v[0], v[1]); og.y = pack2(v[2], v[3]);
                    og.z = pack2(v[4], v[5]); og.w = pack2(v[6], v[7]);
                    Wf4[((size_t)j * NKB + (k0w >> 5)) * 64 + Lw] = og;
                }
            }
            #pragma unroll
            for (int p = 0; p < 2; p++) {
                int o = p * 512 + t;
                if (o < 640) {
                    int j = o >> 6, i = (o >> 3) & 7, cc = o & 7;
                    unsigned int r8[8];
                    #pragma unroll
                    for (int h = 0; h < 8; h++)
                        r8[h] = pack2(lds[cc * 1280 + j * 128 + (2 * h) * 8 + i],
                                      lds[cc * 1280 + j * 128 + (2 * h + 1) * 8 + i]);
                    unsigned short* dst = W2s + ((size_t)(j * 8 + i) * C_ + c0 + cc) * 16;
                    *(uint4*)dst       = make_uint4(r8[0], r8[1], r8[2], r8[3]);
                    *(uint4*)(dst + 8) = make_uint4(r8[4], r8[5], r8[6], r8[7]);
                }
            }
        } else {                                // ---- zero b_ij
            for (int idx = t; idx < C_ * J_; idx += 512) bij[idx] = 0.0f;
        }
        __syncthreads();    // protect lds reuse across sequential tasks
    }

    // ---------------- routing: s0 | t0 | s1 | t1 | s2 ----------------------
    gsync(bar, 1 * NBLK);
    sgemm_phase<0>(lds, (const short8*)Wf_f, (const short8*)Bs_f, bij,
                   (unsigned short*)Vf_f, out);
    gsync(bar, 2 * NBLK);
    tgemm_phase((const short8*)Vf_f, (const short8*)Bt_f, W2s, bij);
    gsync(bar, 3 * NBLK);
    sgemm_phase<1>(lds, (const short8*)Wf_f, (const short8*)Bs_f, bij,
                   (unsigned short*)Vf_f, out);
    gsync(bar, 4 * NBLK);
    tgemm_phase((const short8*)Vf_f, (const short8*)Bt_f, W2s, bij);
    gsync(bar, 5 * NBLK);
    sgemm_phase<2>(lds, (const short8*)Wf_f, (const short8*)Bs_f, bij,
                   (unsigned short*)Vf_f, out);
}

// ---------------------------------------------------------------------------
extern "C" void kernel_launch(void* const* d_in, const int* in_sizes, int n_in,
                              void* d_out, int out_size, void* d_ws, size_t ws_size,
                              hipStream_t stream) {
    const float* x = (const float*)d_in[0];   // [512][8][1152]
    const float* W = (const float*)d_in[1];   // [1152][10][16][8]
    float* out = (float*)d_out;               // [512][10][16][1]
    float* ws  = (float*)d_ws;

    // barrier counter lives just past bij (ws poisoned by harness -> memset)
    int* bar = (int*)(ws + 2359296 * 2 + 737280 * 2 + 40960 + 11520);
    hipMemsetAsync(bar, 0, 256, stream);

    k_fused<<<NBLK, 512, 0, stream>>>(x, W, ws, out, bar);
}

// Round 2
// 276.261 us; speedup vs baseline: 1.6403x; 1.6403x over previous
//
#include <hip/hip_runtime.h>
#include <hip/hip_bf16.h>
#include <math.h>

#define B_   512
#define I_   8
#define C_   1152
#define J_   10
#define S_   16
#define K1   9216
#define NKB  288     // sgemm K-blocks (K=9216/32)
#define KBT  16      // tgemm K-blocks (K=512/32)
#define NBLK 320     // persistent grid: 32 nt-tiles x 10 j

typedef short short8 __attribute__((ext_vector_type(8)));
typedef float floatx4 __attribute__((ext_vector_type(4)));

__device__ inline unsigned short f2bf(float f) {
    unsigned int u = __float_as_uint(f);
    return (unsigned short)((u + 0x7FFFu + ((u >> 16) & 1u)) >> 16);
}
__device__ inline unsigned int pack2(float a, float b) {
    __hip_bfloat162 h = __float22bfloat162_rn(float2{a, b});
    return *reinterpret_cast<unsigned int*>(&h);
}

// ---------------------------------------------------------------------------
// Grid-wide barrier, v2.
// R1's version spun on an ACQUIRE agent load -> buffer_inv + waitcnt EVERY
// iteration -> 320 spinners continuously invalidated all L1/L2 while other
// blocks worked (404us, 95% idle). Fix: RELAXED spin (plain coherent load,
// no invalidate), then ONE __threadfence() (wbl2+inv) after exit.
// Writer side: release fetch_add already writes back the XCD L2 to LLC, so
// no pre-fence needed. Monotone epoch targets -> no reset, no ABA.
__device__ inline void gsync(int* bar, int target) {
    __syncthreads();
    if (threadIdx.x == 0) {
        __hip_atomic_fetch_add(bar, 1, __ATOMIC_RELEASE, __HIP_MEMORY_SCOPE_AGENT);
        while (__hip_atomic_load(bar, __ATOMIC_RELAXED, __HIP_MEMORY_SCOPE_AGENT) < target)
            __builtin_amdgcn_s_sleep(8);
        __threadfence();   // single acquire: invalidate stale L1/L2 once
    }
    __syncthreads();
}

// ---------------------------------------------------------------------------
// SGEMM phase (verbatim body from verified k_sgemm_f).
// MODE 0: uniform cnorm=0.1; MODE 1: softmax fold -> Vf; MODE 2: fold -> out.
template<int MODE>
__device__ __forceinline__ void sgemm_phase(
        float* smf,
        const short8* __restrict__ Wf, const short8* __restrict__ Bs,
        const float* __restrict__ b_ij,
        unsigned short* __restrict__ Vf, float* __restrict__ out) {
    const int t = threadIdx.x, w = t >> 6, L = t & 63, quad = L >> 4;
    const int j  = blockIdx.x >> 5;      // 0..9
    const int nt = blockIdx.x & 31;      // 16-b tile, 0..31

    if (MODE) {
        for (int c = t; c < C_; c += 512) {
            float bv[J_], mx = -1e30f;
            #pragma unroll
            for (int jj = 0; jj < J_; jj++) {
                bv[jj] = b_ij[c * J_ + jj]; mx = fmaxf(mx, bv[jj]);
            }
            float sum = 0.0f;
            #pragma unroll
            for (int jj = 0; jj < J_; jj++) sum += __expf(bv[jj] - mx);
            smf[c] = __expf(bv[j] - mx) / sum;
        }
    }
    __syncthreads();

    const short8* pA = Wf + ((size_t)j * NKB + w * 36) * 64 + L;
    const short8* pB = Bs + ((size_t)nt * NKB + w * 36) * 64 + L;
    floatx4 acc = {0.f, 0.f, 0.f, 0.f};
    if (MODE) {
        #pragma unroll 6
        for (int i = 0; i < 36; i++) {
            short8 a = pA[i * 64];
            const int cb = i * 32 + quad * 8;     // (w*36*32) % 1152 == 0
            float4 cl = *(const float4*)&smf[cb];
            float4 ch = *(const float4*)&smf[cb + 4];
            float cn8[8] = {cl.x, cl.y, cl.z, cl.w, ch.x, ch.y, ch.z, ch.w};
            unsigned int* au = (unsigned int*)&a;
            short8 a2; unsigned int* ao = (unsigned int*)&a2;
            #pragma unroll
            for (int h = 0; h < 4; h++) {
                float f0 = __uint_as_float(au[h] << 16)         * cn8[2 * h];
                float f1 = __uint_as_float(au[h] & 0xffff0000u) * cn8[2 * h + 1];
                ao[h] = pack2(f0, f1);
            }
            acc = __builtin_amdgcn_mfma_f32_16x16x32_bf16(a2, pB[i * 64], acc, 0, 0, 0);
        }
    } else {
        #pragma unroll 6
        for (int i = 0; i < 36; i++)
            acc = __builtin_amdgcn_mfma_f32_16x16x32_bf16(pA[i * 64], pB[i * 64], acc, 0, 0, 0);
    }

    const int col = L & 15, rw = quad << 2;
    float* base = &smf[1152 + w * 256];
    #pragma unroll
    for (int r = 0; r < 4; r++)
        base[(rw + r) * 16 + col] = acc[r];
    __syncthreads();

    if (t < 16) {                        // reduce 8 partials + squash (bl = t)
        float sv[S_]; float msq = 0.f;
        #pragma unroll
        for (int s = 0; s < S_; s++) {
            float a = 0.f;
            #pragma unroll
            for (int w8 = 0; w8 < 8; w8++)
                a += smf[1152 + w8 * 256 + s * 16 + t];
            if (MODE == 0) a *= 0.1f;
            sv[s] = a; msq += a * a;
        }
        const float scale = msq / ((1.f + msq) * sqrtf(msq));
        const int b = nt * 16 + t;       // global b (0..511)
        if (MODE < 2) {
            const int kb = b >> 5, lh = (b >> 3) & 3, e = b & 7;
            #pragma unroll
            for (int s = 0; s < S_; s++)
                Vf[((size_t)(j * KBT + kb) * 64 + (s | (lh << 4))) * 8 + e] =
                    f2bf(sv[s] * scale);
        } else {
            float o16[S_];
            #pragma unroll
            for (int s = 0; s < S_; s++) o16[s] = sv[s] * scale;
            float* dst = &out[((size_t)b * J_ + j) * S_];
            #pragma unroll
            for (int r4 = 0; r4 < 4; r4++)
                *(float4*)(dst + r4 * 4) = *(float4*)(o16 + r4 * 4);
        }
    }
    // no trailing __syncthreads: the following gsync() provides it
}

// ---------------------------------------------------------------------------
// TGEMM phase (verbatim body): 5760 wave-tasks redistributed over 2560 waves.
__device__ __forceinline__ void tgemm_phase(
        const short8* __restrict__ Vf, const short8* __restrict__ Bt,
        const unsigned short* __restrict__ W2, float* __restrict__ b_ij) {
    const int t = threadIdx.x, w = t >> 6, L = t & 63;
    for (int tau = blockIdx.x * 8 + w; tau < 5760; tau += NBLK * 8) {
        const int j = tau / 576, nt = tau % 576;
        const short8* pA = Vf + (size_t)j * KBT * 64 + L;
        const short8* pB = Bt + (size_t)nt * KBT * 64 + L;
        floatx4 a = {0.f, 0.f, 0.f, 0.f};
        #pragma unroll
        for (int kb = 0; kb < KBT; kb++)
            a = __builtin_amdgcn_mfma_f32_16x16x32_bf16(pA[kb * 64], pB[kb * 64], a, 0, 0, 0);
        const int col = L & 15, rw = (L >> 4) << 2;
        const int i = nt / 72;
        const int c = (nt % 72) * 16 + col;
        const unsigned short* wp = W2 + ((size_t)(j * 8 + i) * C_ + c) * 16 + rw;
        uint2 wv = *(const uint2*)wp;
        float p = a[0] * __uint_as_float((unsigned int)wv.x << 16)
                + a[1] * __uint_as_float(wv.x & 0xffff0000u)
                + a[2] * __uint_as_float((unsigned int)wv.y << 16)
                + a[3] * __uint_as_float(wv.y & 0xffff0000u);
        p += __shfl_xor(p, 16);
        p += __shfl_xor(p, 32);
        if ((L >> 4) == 0)
            atomicAdd(&b_ij[c * J_ + j], p * (1.0f / 512.f));
    }
}

// ---------------------------------------------------------------------------
// Fused persistent kernel: pack | s0 | t0 | s1 | t1 | s2 with 5 grid syncs.
__global__ __launch_bounds__(512, 4) void k_fused(
        const float* __restrict__ x, const float* __restrict__ W,
        float* __restrict__ ws, float* __restrict__ out, int* __restrict__ bar) {
    __shared__ float lds[10240];
    const int t = threadIdx.x, w = t >> 6, L = t & 63, quad = L >> 4;

    float* Bs_f = ws;                    // bf16 Bs   (9.4 MB region)
    float* Bt_f = Bs_f + 2359296;        // bf16 Bt
    float* Wf_f = Bt_f + 2359296;        // bf16 Wf
    float* W2_f = Wf_f + 737280;         // bf16 W2
    float* Vf_f = W2_f + 737280;         // bf16 Vf
    float* bij  = Vf_f + 40960;          // f32 b_ij

    uint4* Bs4 = (uint4*)Bs_f;
    uint4* Bt4 = (uint4*)Bt_f;
    uint4* Wf4 = (uint4*)Wf_f;
    unsigned short* W2s = (unsigned short*)W2_f;

    // ---------------- phase P: pack (721 tasks over 320 blocks) ------------
    for (int task = blockIdx.x; task < 721; task += NBLK) {
        if (task < 576) {                       // ---- x tile -> Bs + Bt
            const int bt = task / 36, kt = task % 36;
            const int b0 = bt * 32, k0 = kt * 256;
            #pragma unroll
            for (int p = 0; p < 4; p++) {
                int f4 = p * 512 + t;
                int row = f4 >> 6, c4 = (f4 & 63) << 2;
                *(float4*)&lds[row * 260 + c4] =
                    *(const float4*)&x[(size_t)(b0 + row) * K1 + k0 + c4];
            }
            __syncthreads();
            #pragma unroll
            for (int p = 0; p < 2; p++) {
                const int bl = p * 16 + (L & 15);
                const float* s = &lds[bl * 260 + w * 32 + quad * 8];
                uint4 o;
                o.x = pack2(s[0], s[1]); o.y = pack2(s[2], s[3]);
                o.z = pack2(s[4], s[5]); o.w = pack2(s[6], s[7]);
                Bs4[((size_t)(bt * 2 + p) * NKB + kt * 8 + w) * 64 + L] = o;
            }
            #pragma unroll
            for (int p = 0; p < 2; p++) {
                const int ntl = w * 2 + p;
                const int nl = ntl * 16 + (L & 15);
                float v[8];
                #pragma unroll
                for (int e = 0; e < 8; e++) v[e] = lds[(quad * 8 + e) * 260 + nl];
                uint4 o;
                o.x = pack2(v[0], v[1]); o.y = pack2(v[2], v[3]);
                o.z = pack2(v[4], v[5]); o.w = pack2(v[6], v[7]);
                Bt4[((size_t)(kt * 16 + ntl) * KBT + bt) * 64 + L] = o;
            }
        } else if (task < 720) {                // ---- W chunk -> Wf + W2
            const int c0 = (task - 576) * 8;
            #pragma unroll
            for (int p = 0; p < 5; p++) {
                int f4 = p * 512 + t;
                int cc = f4 / 320, off4 = (f4 % 320) << 2;
                *(float4*)&lds[cc * 1280 + off4] =
                    *(const float4*)&W[(size_t)(c0 + cc) * 1280 + off4];
            }
            __syncthreads();
            #pragma unroll
            for (int p = 0; p < 3; p++) {
                int o = p * 512 + t;
                if (o < 1280) {
                    int j = o >> 7, i = (o >> 4) & 7, m = o & 15;
                    int k0w = i * C_ + c0;
                    int Lw = m | (((k0w >> 3) & 3) << 4);
                    float v[8];
                    #pragma unroll
                    for (int e = 0; e < 8; e++)
                        v[e] = lds[e * 1280 + j * 128 + m * 8 + i];
                    uint4 og;
                    og.x = pack2(v[0], v[1]); og.y = pack2(v[2], v[3]);
                    og.z = pack2(v[4], v[5]); og.w = pack2(v[6], v[7]);
                    Wf4[((size_t)j * NKB + (k0w >> 5)) * 64 + Lw] = og;
                }
            }
            #pragma unroll
            for (int p = 0; p < 2; p++) {
                int o = p * 512 + t;
                if (o < 640) {
                    int j = o >> 6, i = (o >> 3) & 7, cc = o & 7;
                    unsigned int r8[8];
                    #pragma unroll
                    for (int h = 0; h < 8; h++)
                        r8[h] = pack2(lds[cc * 1280 + j * 128 + (2 * h) * 8 + i],
                                      lds[cc * 1280 + j * 128 + (2 * h + 1) * 8 + i]);
                    unsigned short* dst = W2s + ((size_t)(j * 8 + i) * C_ + c0 + cc) * 16;
                    *(uint4*)dst       = make_uint4(r8[0], r8[1], r8[2], r8[3]);
                    *(uint4*)(dst + 8) = make_uint4(r8[4], r8[5], r8[6], r8[7]);
                }
            }
        } else {                                // ---- zero b_ij
            for (int idx = t; idx < C_ * J_; idx += 512) bij[idx] = 0.0f;
        }
        __syncthreads();    // protect lds reuse across sequential tasks
    }

    // ---------------- routing: s0 | t0 | s1 | t1 | s2 ----------------------
    gsync(bar, 1 * NBLK);
    sgemm_phase<0>(lds, (const short8*)Wf_f, (const short8*)Bs_f, bij,
                   (unsigned short*)Vf_f, out);
    gsync(bar, 2 * NBLK);
    tgemm_phase((const short8*)Vf_f, (const short8*)Bt_f, W2s, bij);
    gsync(bar, 3 * NBLK);
    sgemm_phase<1>(lds, (const short8*)Wf_f, (const short8*)Bs_f, bij,
                   (unsigned short*)Vf_f, out);
    gsync(bar, 4 * NBLK);
    tgemm_phase((const short8*)Vf_f, (const short8*)Bt_f, W2s, bij);
    gsync(bar, 5 * NBLK);
    sgemm_phase<2>(lds, (const short8*)Wf_f, (const short8*)Bs_f, bij,
                   (unsigned short*)Vf_f, out);
}

// ---------------------------------------------------------------------------
extern "C" void kernel_launch(void* const* d_in, const int* in_sizes, int n_in,
                              void* d_out, int out_size, void* d_ws, size_t ws_size,
                              hipStream_t stream) {
    const float* x = (const float*)d_in[0];   // [512][8][1152]
    const float* W = (const float*)d_in[1];   // [1152][10][16][8]
    float* out = (float*)d_out;               // [512][10][16][1]
    float* ws  = (float*)d_ws;

    // barrier counter lives just past bij (ws poisoned by harness -> memset)
    int* bar = (int*)(ws + 2359296 * 2 + 737280 * 2 + 40960 + 11520);
    hipMemsetAsync(bar, 0, 256, stream);

    k_fused<<<NBLK, 512, 0, stream>>>(x, W, ws, out, bar);
}

// Round 4
// 129.857 us; speedup vs baseline: 3.4896x; 2.1274x over previous
//
#include <hip/hip_runtime.h>
#include <hip/hip_bf16.h>
#include <math.h>

#define B_  512
#define I_  8
#define C_  1152
#define J_  10
#define S_  16
#define K1  9216
#define NKB 288     // sgemm K-blocks (K=9216/32)
#define KBT 16      // tgemm K-blocks (K=512/32)

typedef short short8 __attribute__((ext_vector_type(8)));
typedef float floatx4 __attribute__((ext_vector_type(4)));

__device__ inline unsigned short f2bf(float f) {
    unsigned int u = __float_as_uint(f);
    return (unsigned short)((u + 0x7FFFu + ((u >> 16) & 1u)) >> 16);
}
__device__ inline unsigned int pack2(float a, float b) {
    __hip_bfloat162 h = __float22bfloat162_rn(float2{a, b});
    return *reinterpret_cast<unsigned int*>(&h);
}

// ---------------------------------------------------------------------------
// PACK: 721 blocks x 512 threads (reads x once; zeroes b_ij). Verbatim R0.
__global__ __launch_bounds__(512) void k_pack(const float* __restrict__ x,
                                              const float* __restrict__ W,
                                              uint4* __restrict__ Bs,
                                              uint4* __restrict__ Bt,
                                              uint4* __restrict__ Wf,
                                              unsigned short* __restrict__ W2,
                                              float* __restrict__ b_ij) {
    __shared__ float lds[10240];
    const int task = blockIdx.x;
    const int t = threadIdx.x;
    const int w = t >> 6, L = t & 63, quad = L >> 4;

    if (task < 576) {                       // ---- x tile -> Bs + Bt
        const int bt = task / 36, kt = task % 36;
        const int b0 = bt * 32, k0 = kt * 256;
        #pragma unroll
        for (int p = 0; p < 4; p++) {
            int f4 = p * 512 + t;
            int row = f4 >> 6, c4 = (f4 & 63) << 2;
            *(float4*)&lds[row * 260 + c4] =
                *(const float4*)&x[(size_t)(b0 + row) * K1 + k0 + c4];
        }
        __syncthreads();
        #pragma unroll
        for (int p = 0; p < 2; p++) {
            const int bl = p * 16 + (L & 15);
            const float* s = &lds[bl * 260 + w * 32 + quad * 8];
            uint4 o;
            o.x = pack2(s[0], s[1]); o.y = pack2(s[2], s[3]);
            o.z = pack2(s[4], s[5]); o.w = pack2(s[6], s[7]);
            Bs[((size_t)(bt * 2 + p) * NKB + kt * 8 + w) * 64 + L] = o;
        }
        #pragma unroll
        for (int p = 0; p < 2; p++) {
            const int ntl = w * 2 + p;
            const int nl = ntl * 16 + (L & 15);
            float v[8];
            #pragma unroll
            for (int e = 0; e < 8; e++) v[e] = lds[(quad * 8 + e) * 260 + nl];
            uint4 o;
            o.x = pack2(v[0], v[1]); o.y = pack2(v[2], v[3]);
            o.z = pack2(v[4], v[5]); o.w = pack2(v[6], v[7]);
            Bt[((size_t)(kt * 16 + ntl) * KBT + bt) * 64 + L] = o;
        }
    } else if (task < 720) {                // ---- W chunk -> Wf + W2
        const int c0 = (task - 576) * 8;
        #pragma unroll
        for (int p = 0; p < 5; p++) {
            int f4 = p * 512 + t;
            int cc = f4 / 320, off4 = (f4 % 320) << 2;
            *(float4*)&lds[cc * 1280 + off4] =
                *(const float4*)&W[(size_t)(c0 + cc) * 1280 + off4];
        }
        __syncthreads();
        #pragma unroll
        for (int p = 0; p < 3; p++) {
            int o = p * 512 + t;
            if (o < 1280) {
                int j = o >> 7, i = (o >> 4) & 7, m = o & 15;
                int k0w = i * C_ + c0;
                int Lw = m | (((k0w >> 3) & 3) << 4);
                float v[8];
                #pragma unroll
                for (int e = 0; e < 8; e++)
                    v[e] = lds[e * 1280 + j * 128 + m * 8 + i];
                uint4 og;
                og.x = pack2(v[0], v[1]); og.y = pack2(v[2], v[3]);
                og.z = pack2(v[4], v[5]); og.w = pack2(v[6], v[7]);
                Wf[((size_t)j * NKB + (k0w >> 5)) * 64 + Lw] = og;
            }
        }
        #pragma unroll
        for (int p = 0; p < 2; p++) {
            int o = p * 512 + t;
            if (o < 640) {
                int j = o >> 6, i = (o >> 3) & 7, cc = o & 7;
                unsigned int r8[8];
                #pragma unroll
                for (int h = 0; h < 8; h++)
                    r8[h] = pack2(lds[cc * 1280 + j * 128 + (2 * h) * 8 + i],
                                  lds[cc * 1280 + j * 128 + (2 * h + 1) * 8 + i]);
                unsigned short* dst = W2 + ((size_t)(j * 8 + i) * C_ + c0 + cc) * 16;
                *(uint4*)dst       = make_uint4(r8[0], r8[1], r8[2], r8[3]);
                *(uint4*)(dst + 8) = make_uint4(r8[4], r8[5], r8[6], r8[7]);
            }
        }
    } else {                                // ---- zero b_ij
        for (int idx = t; idx < C_ * J_; idx += 512) b_ij[idx] = 0.0f;
    }
}

// ---------------------------------------------------------------------------
// SGEMM + fused fold + reduce + squash. 320 blocks x 512 thr (8-way K-split).
// XCD-aware task decode (assumes bid%8 -> XCD round-robin): each XCD owns
// 8 nt x 5 j  =>  Bs 2.36MB + Wf 1.48MB = 3.84MB working set, fits 4MB L2.
// mode 0: uniform cnorm=0.1; mode 1: softmax fold -> Vf; mode 2: fold -> out.
__global__ __launch_bounds__(512) void k_sgemm_f(const short8* __restrict__ Wf,
                                                 const short8* __restrict__ Bs,
                                                 const float* __restrict__ b_ij,
                                                 unsigned short* __restrict__ Vf,
                                                 float* __restrict__ out,
                                                 int mode) {
    __shared__ float smf[1152 + 2048];   // cn[1152] + parts[8 waves][256]
    const int t = threadIdx.x, w = t >> 6, L = t & 63, quad = L >> 4;
    const int bid = blockIdx.x;
    const int xcd = bid & 7, sl = bid >> 3;     // sl in [0,40)
    const int j  = 5 * (xcd >> 2) + sl % 5;     // 0..9
    const int nt = 8 * (xcd & 3) + sl / 5;      // 16-b tile, 0..31

    if (mode) {
        for (int c = t; c < C_; c += 512) {
            float bv[J_], mx = -1e30f;
            #pragma unroll
            for (int jj = 0; jj < J_; jj++) {
                bv[jj] = b_ij[c * J_ + jj]; mx = fmaxf(mx, bv[jj]);
            }
            float sum = 0.0f;
            #pragma unroll
            for (int jj = 0; jj < J_; jj++) sum += __expf(bv[jj] - mx);
            smf[c] = __expf(bv[j] - mx) / sum;
        }
    }
    __syncthreads();

    const short8* pA = Wf + ((size_t)j * NKB + w * 36) * 64 + L;
    const short8* pB = Bs + ((size_t)nt * NKB + w * 36) * 64 + L;
    floatx4 acc = {0.f, 0.f, 0.f, 0.f};
    if (mode) {
        #pragma unroll 6
        for (int i = 0; i < 36; i++) {
            short8 a = pA[i * 64];
            const int cb = i * 32 + quad * 8;     // (w*36*32) % 1152 == 0
            float4 cl = *(const float4*)&smf[cb];
            float4 ch = *(const float4*)&smf[cb + 4];
            float cn8[8] = {cl.x, cl.y, cl.z, cl.w, ch.x, ch.y, ch.z, ch.w};
            unsigned int* au = (unsigned int*)&a;
            short8 a2; unsigned int* ao = (unsigned int*)&a2;
            #pragma unroll
            for (int h = 0; h < 4; h++) {
                float f0 = __uint_as_float(au[h] << 16)         * cn8[2 * h];
                float f1 = __uint_as_float(au[h] & 0xffff0000u) * cn8[2 * h + 1];
                ao[h] = pack2(f0, f1);
            }
            acc = __builtin_amdgcn_mfma_f32_16x16x32_bf16(a2, pB[i * 64], acc, 0, 0, 0);
        }
    } else {
        #pragma unroll 6
        for (int i = 0; i < 36; i++)
            acc = __builtin_amdgcn_mfma_f32_16x16x32_bf16(pA[i * 64], pB[i * 64], acc, 0, 0, 0);
    }

    const int col = L & 15, rw = quad << 2;
    float* base = &smf[1152 + w * 256];
    #pragma unroll
    for (int r = 0; r < 4; r++)
        base[(rw + r) * 16 + col] = acc[r];
    __syncthreads();

    if (t < 16) {                        // reduce 8 partials + squash (bl = t)
        float sv[S_]; float msq = 0.f;
        #pragma unroll
        for (int s = 0; s < S_; s++) {
            float a = 0.f;
            #pragma unroll
            for (int w8 = 0; w8 < 8; w8++)
                a += smf[1152 + w8 * 256 + s * 16 + t];
            if (mode == 0) a *= 0.1f;
            sv[s] = a; msq += a * a;
        }
        const float scale = msq / ((1.f + msq) * sqrtf(msq));
        const int b = nt * 16 + t;       // global b (0..511)
        if (mode < 2) {
            const int kb = b >> 5, lh = (b >> 3) & 3, e = b & 7;
            #pragma unroll
            for (int s = 0; s < S_; s++)
                Vf[((size_t)(j * KBT + kb) * 64 + (s | (lh << 4))) * 8 + e] =
                    f2bf(sv[s] * scale);
        } else {
            float o16[S_];
            #pragma unroll
            for (int s = 0; s < S_; s++) o16[s] = sv[s] * scale;
            float* dst = &out[((size_t)b * J_ + j) * S_];
            #pragma unroll
            for (int r4 = 0; r4 < 4; r4++)
                *(float4*)(dst + r4 * 4) = *(float4*)(o16 + r4 * 4);
        }
    }
}

// ---------------------------------------------------------------------------
// TGEMM + fused b_ij update, ATOMIC-FREE. grid 720 x 512 thr.
// Wave w owns i = w (nt = w*72 + cblk): one block covers all 8 i's for its
// 16 c's => 8-way LDS reduce, then non-atomic READ-ADD-STORE (the reference
// b_ij update is CUMULATIVE across routing rounds — R3's plain store dropped
// the previous round's value; exactly-one-block-per-cell makes RMW safe).
// XCD-aware decode: each XCD owns 9 cblk x 10 j => Bt 1.15MB + Vf 164KB.
__global__ __launch_bounds__(512) void k_tgemm_bup(const short8* __restrict__ Vf,
                                                   const short8* __restrict__ Bt,
                                                   const unsigned short* __restrict__ W2,
                                                   float* __restrict__ b_ij) {
    __shared__ float red[8][16];
    const int t = threadIdx.x, w = t >> 6, L = t & 63;
    const int bid = blockIdx.x;
    const int xcd = bid & 7, sl = bid >> 3;      // sl in [0,90)
    const int cblk = 9 * xcd + sl / 10;          // 0..71
    const int j    = sl % 10;                    // 0..9
    const int nt   = w * 72 + cblk;              // wave w handles i = w
    const short8* pA = Vf + (size_t)j * KBT * 64 + L;
    const short8* pB = Bt + (size_t)nt * KBT * 64 + L;
    floatx4 a = {0.f, 0.f, 0.f, 0.f};
    #pragma unroll
    for (int kb = 0; kb < KBT; kb++)
        a = __builtin_amdgcn_mfma_f32_16x16x32_bf16(pA[kb * 64], pB[kb * 64], a, 0, 0, 0);
    const int col = L & 15, rw = (L >> 4) << 2;
    const int c = cblk * 16 + col;
    const unsigned short* wp = W2 + ((size_t)(j * 8 + w) * C_ + c) * 16 + rw;
    uint2 wv = *(const uint2*)wp;
    float p = a[0] * __uint_as_float((unsigned int)wv.x << 16)
            + a[1] * __uint_as_float(wv.x & 0xffff0000u)
            + a[2] * __uint_as_float((unsigned int)wv.y << 16)
            + a[3] * __uint_as_float(wv.y & 0xffff0000u);
    p += __shfl_xor(p, 16);              // sum s-quads across the wave
    p += __shfl_xor(p, 32);
    if ((L >> 4) == 0) red[w][col] = p;  // per-wave partial (i = w)
    __syncthreads();
    if (t < 16) {
        float acc = 0.f;
        #pragma unroll
        for (int w8 = 0; w8 < 8; w8++) acc += red[w8][t];
        const size_t idx = (size_t)(cblk * 16 + t) * J_ + j;
        b_ij[idx] += acc * (1.0f / 512.f);   // CUMULATIVE (matches reference)
    }
}

// ---------------------------------------------------------------------------
extern "C" void kernel_launch(void* const* d_in, const int* in_sizes, int n_in,
                              void* d_out, int out_size, void* d_ws, size_t ws_size,
                              hipStream_t stream) {
    const float* x = (const float*)d_in[0];   // [512][8][1152]
    const float* W = (const float*)d_in[1];   // [1152][10][16][8]
    float* out = (float*)d_out;               // [512][10][16][1]
    float* ws  = (float*)d_ws;

    float* Bs_f = ws;                    // 2,359,296
    float* Bt_f = Bs_f + 2359296;        // 2,359,296
    float* Wf_f = Bt_f + 2359296;        //   737,280
    float* W2_f = Wf_f + 737280;         //   737,280
    float* Vf_f = W2_f + 737280;         //    40,960
    float* bij  = Vf_f + 40960;          //    11,520
    // total ~25 MB

    k_pack<<<721, 512, 0, stream>>>(x, W, (uint4*)Bs_f, (uint4*)Bt_f,
                                    (uint4*)Wf_f, (unsigned short*)W2_f, bij);

    k_sgemm_f<<<320, 512, 0, stream>>>(
        (const short8*)Wf_f, (const short8*)Bs_f, bij,
        (unsigned short*)Vf_f, out, 0);
    k_tgemm_bup<<<720, 512, 0, stream>>>(
        (const short8*)Vf_f, (const short8*)Bt_f, (const unsigned short*)W2_f, bij);

    k_sgemm_f<<<320, 512, 0, stream>>>(
        (const short8*)Wf_f, (const short8*)Bs_f, bij,
        (unsigned short*)Vf_f, out, 1);
    k_tgemm_bup<<<720, 512, 0, stream>>>(
        (const short8*)Vf_f, (const short8*)Bt_f, (const unsigned short*)W2_f, bij);

    k_sgemm_f<<<320, 512, 0, stream>>>(
        (const short8*)Wf_f, (const short8*)Bs_f, bij,
        (unsigned short*)Vf_f, out, 2);
}